// Round 1
// baseline (221.376 us; speedup 1.0000x reference)
//
#include <hip/hip_runtime.h>
#include <stdint.h>

typedef unsigned long long u64;
typedef unsigned int u32;

#define N_ANCH 36864
#define WGRID 64
#define A_PER 9
#define KTOP 6000
#define NOUT 300
#define NBIN 5120       // max used bin = 4352 (binof), keep multiple of 1024 for scan
#define NCHK 94         // ceil(6000/64) = u64 words per mask row
#define INF_BIN 0       // -inf / invalid scores
#define PCAP 8          // pending kept-row load buffers (register, static-indexed)

// Base anchors from py-faster-rcnn generate_anchors (scales 8,16,32; ratios .5,1,2), exact integers.
__constant__ float c_ax1[9] = {-84.f,-176.f,-360.f,-56.f,-120.f,-248.f,-36.f,-80.f,-168.f};
__constant__ float c_ay1[9] = {-40.f,-88.f,-184.f,-56.f,-120.f,-248.f,-80.f,-168.f,-344.f};
__constant__ float c_aw[9]  = {184.f,368.f,736.f,128.f,256.f,512.f,88.f,176.f,352.f};
__constant__ float c_ah[9]  = {96.f,192.f,384.f,128.f,256.f,512.f,176.f,352.f,704.f};

// Monotone (order-preserving) bin of the ordered-float score word u = key>>32.
// Scores sigmoid(l1-l0) concentrate in [0.5,1) = ONE float octave -> give that
// octave 4096 bins (12 mantissa bits); everything below is coarse and can never
// straddle the rank-6000 boundary (~15500 of ~31000 valid scores are >= 0.5).
__device__ __forceinline__ u32 binof(u32 u) {
    if (u < 0x80000000u) return 0u;                          // -inf (invalid)
    if (u < 0xBF000000u) return 1u + ((u - 0x80000000u) >> 22);   // s<0.5 : 1..252
    return 256u + ((u - 0xBF000000u) >> 11);                 // s>=0.5: 256..4352
}

// 36 blocks x 1024 threads = 36864. Per-block LDS histogram (20 KB).
__global__ __launch_bounds__(1024) void proposal_kernel(const float* __restrict__ cls,
                                                        const float* __restrict__ dlt,
                                                        u64* __restrict__ keys,
                                                        float4* __restrict__ boxes,
                                                        u32* __restrict__ hist) {
    __shared__ u32 lh[NBIN];
    const int t = threadIdx.x;
    for (int b = t; b < NBIN; b += 1024) lh[b] = 0;
    __syncthreads();

    int i = blockIdx.x * 1024 + t;
    int a  = i % A_PER;
    int hw = i / A_PER;
    int wx = hw % WGRID;
    int hy = hw / WGRID;

    // softmax over 2 logits, class-1 prob (matches jax.nn.softmax: subtract max)
    float2 lp = *(const float2*)(cls + hw * 18 + 2 * a);   // 8B-aligned (even float offset)
    float l0 = lp.x, l1 = lp.y;
    float m  = fmaxf(l0, l1);
    float e0 = expf(l0 - m), e1 = expf(l1 - m);
    float s  = e1 / (e0 + e1);

    float4 dd = *(const float4*)(dlt + hw * 36 + 4 * a);   // 16B-aligned
    float dx = dd.x, dy = dd.y, dw = dd.z, dh = dd.w;
    float aw = c_aw[a], ah = c_ah[a];
    float axc = (c_ax1[a] + 16.f * (float)wx) + 0.5f * aw;
    float ayc = (c_ay1[a] + 16.f * (float)hy) + 0.5f * ah;

    float pxc = dx * aw + axc;
    float pyc = dy * ah + ayc;
    float pw  = expf(dw) * aw;
    float ph  = expf(dh) * ah;
    float x1 = pxc - 0.5f * pw, y1 = pyc - 0.5f * ph;
    float x2 = pxc + 0.5f * pw, y2 = pyc + 0.5f * ph;
    x1 = fminf(fmaxf(x1, 0.f), 1023.f);
    x2 = fminf(fmaxf(x2, 0.f), 1023.f);
    y1 = fminf(fmaxf(y1, 0.f), 1023.f);
    y2 = fminf(fmaxf(y2, 0.f), 1023.f);
    bool valid = ((x2 - x1 + 1.f) >= 16.f) && ((y2 - y1 + 1.f) >= 16.f);
    float sc = valid ? s : -__builtin_huge_valf();

    // order-preserving float->uint; key = (ord(score)<<32) | ~index  (desc score, asc index)
    u32 sb  = __float_as_uint(sc);
    u32 ord = (sb & 0x80000000u) ? ~sb : (sb | 0x80000000u);
    u64 key = ((u64)ord << 32) | (u32)(~(u32)i);
    keys[i]  = key;
    boxes[i] = make_float4(x1, y1, x2, y2);

    // histogram: wave-aggregate the -inf bin, LDS atomics for the rest
    u64 infb = __ballot(!valid);
    if (valid) {
        atomicAdd(&lh[binof(ord)], 1u);
    } else {
        int lane = t & 63;
        if (lane == __builtin_ctzll(infb))          // first invalid lane in wave
            atomicAdd(&lh[INF_BIN], (u32)__popcll(infb));
    }
    __syncthreads();
    for (int b = t; b < NBIN; b += 1024) {
        u32 v = lh[b];
        if (v) atomicAdd(&hist[b], v);
    }
}

// Single block: descending exclusive prefix over 5120 bins -> binStart; find E (end of
// boundary bucket straddling rank 6000); init gV=KTOP. (cursor zeroed by memset)
__global__ __launch_bounds__(1024) void scan_kernel(const u32* __restrict__ hist,
                                                    u32* __restrict__ binStart,
                                                    u32* __restrict__ gEV) {
    __shared__ u32 sh[1024];
    int t = threadIdx.x;
    if (t == 0) gEV[1] = KTOP;   // V init (lowered by rank_kernel via atomicMin)
    int hi = NBIN - 1 - 5 * t;   // thread t owns bins [hi-4 .. hi], descending
    u32 cnt[5];
    u32 sum = 0;
#pragma unroll
    for (int k = 0; k < 5; ++k) { cnt[k] = hist[hi - k]; sum += cnt[k]; }
    sh[t] = sum;
    __syncthreads();
    for (int d = 1; d < 1024; d <<= 1) {
        u32 v = (t >= d) ? sh[t - d] : 0;
        __syncthreads();
        sh[t] += v;
        __syncthreads();
    }
    u32 run = sh[t] - sum;   // exclusive (sum of all higher bins)
#pragma unroll
    for (int k = 0; k < 5; ++k) {
        int b = hi - k;
        binStart[b] = run;
        u32 end = run + cnt[k];
        if (run < KTOP && end >= KTOP) gEV[0] = end;   // unique boundary bucket
        run = end;
    }
}

// Scatter keys of buckets that start before rank KTOP into contiguous per-bucket slots.
__global__ void scatter_kernel(const u64* __restrict__ keys,
                               const u32* __restrict__ binStart,
                               u32* __restrict__ cursor,
                               u64* __restrict__ scat) {
    int i = blockIdx.x * blockDim.x + threadIdx.x;
    if (i >= N_ANCH) return;
    u64 k = keys[i];
    u32 b = binof((u32)(k >> 32));
    u32 s = binStart[b];
    if (s < KTOP) {
        u32 p = s + atomicAdd(&cursor[b], 1u);
        scat[p] = k;
    }
}

// Exact rank within bucket by counting larger keys (keys unique); gather topBoxes[rank].
__global__ void rank_kernel(const u64* __restrict__ scat,
                            const u32* __restrict__ binStart,
                            const u32* __restrict__ hist,
                            const float4* __restrict__ boxes,
                            const u32* __restrict__ gEV,
                            float4* __restrict__ topBoxes,
                            int* __restrict__ gV) {
    int i = blockIdx.x * blockDim.x + threadIdx.x;
    u32 E = gEV[0];
    if (i >= (int)E) return;
    u64 k = scat[i];
    u32 b = binof((u32)(k >> 32));
    u32 s = binStart[b], c = hist[b];
    u32 r = s;
    for (u32 j = s; j < s + c; ++j) r += (scat[j] > k) ? 1u : 0u;
    if (r < KTOP) {
        int idx = (int)(~(u32)k);
        topBoxes[r] = boxes[idx];
        if (!(k >> 63)) atomicMin(gV, (int)r);   // first -inf rank => V
    }
}

__device__ __forceinline__ bool iou_gt(float4 a, float areaA, float4 b, float areaB) {
    float ix1 = fmaxf(a.x, b.x), iy1 = fmaxf(a.y, b.y);
    float ix2 = fminf(a.z, b.z), iy2 = fminf(a.w, b.w);
    float iw = fmaxf(ix2 - ix1 + 1.0f, 0.0f);
    float ih = fmaxf(iy2 - iy1 + 1.0f, 0.0f);
    float inter = iw * ih;
    float iou = inter / (areaA + areaB - inter);
    return iou > 0.7f;
}

// Grid-wide pairwise suppression mask (torchvision-style): M[i][cw] bit b set iff
// IoU(box_i, box_{cw*64+b}) > 0.7 and cw*64+b > i. Only cw >= chunk(i) computed/read.
// D0[i] = diagonal word (own chunk, bits > self), D1[i] = diagonal+1 word — stored
// separately so the serial resolve's per-chunk prefetches are coalesced.
// Block = 256 threads: 4 row-chunks sharing one LDS-staged col-chunk. ~18M IoUs on 256 CUs.
__global__ __launch_bounds__(256) void mask_kernel(const float4* __restrict__ topBoxes,
                                                   const u32* __restrict__ gEV,
                                                   u64* __restrict__ M,
                                                   u64* __restrict__ D0,
                                                   u64* __restrict__ D1) {
    const int V = (int)gEV[1];
    const int nch = (V + 63) >> 6;
    const int cw = blockIdx.x;
    const int r0 = blockIdx.y * 4;
    if (cw >= nch || r0 > cw || r0 >= nch) return;   // block-uniform
    __shared__ float4 cb[64];
    __shared__ float ca[64];
    const int t = threadIdx.x;
    const int lane = t & 63;
    if (t < 64) {
        int cj = cw * 64 + t;
        // dummy for cols >= V: inverted box -> intersection 0 -> never suppresses
        float4 b = (cj < V) ? topBoxes[cj] : make_float4(0.f, 0.f, -8.f, -8.f);
        cb[t] = b;
        ca[t] = (b.z - b.x + 1.f) * (b.w - b.y + 1.f);
    }
    __syncthreads();
    const int r = r0 + (t >> 6);
    if (r > cw || r >= nch) return;
    const int i = r * 64 + lane;
    if (i >= V) return;
    float4 bi = topBoxes[i];
    float ai = (bi.z - bi.x + 1.f) * (bi.w - bi.y + 1.f);
    u64 m = 0;
#pragma unroll 4
    for (int j = 0; j < 64; ++j)
        if (iou_gt(bi, ai, cb[j], ca[j])) m |= (1ULL << j);
    if (cw == r) { m &= ~((2ULL << lane) - 1ULL); D0[i] = m; }   // keep only j > self; lane 63 -> 0
    if (cw == r + 1) D1[i] = m;
    M[(u64)i * NCHK + cw] = m;
}

// Single block. Phase 1: ONE wave, ZERO barriers — greedy NMS as pure bit-ops over the
// precomputed mask. removed[] lives in registers (lane l holds words l and l+64).
// Latency pipeline: D0/D1 diag words prefetched one chunk ahead (coalesced); `carry`
// (shfl-OR of D1 over this chunk's kept) supplies removed[c+1] so full-row ORs may lag
// one round in pend[] registers (issued end of round c, applied post-resolve round c+1).
// Phase 2: 1024-thread prefix over keepw -> out positions (kept in rank order, then
// suppressed/-inf ties in rank order — same semantics as the previously verified kernel).
__global__ __launch_bounds__(1024) void nms_out_kernel(const float4* __restrict__ topBoxes,
                                                       const u32* __restrict__ gEV,
                                                       const u64* __restrict__ M,
                                                       const u64* __restrict__ D0,
                                                       const u64* __restrict__ D1,
                                                       float* __restrict__ out) {
    __shared__ u64 keepw[NCHK];
    __shared__ u32 scanbuf[1024];
    const int t = threadIdx.x;
    const int lane = t & 63;
    if (t < NCHK) keepw[t] = 0;
    const int V = (int)gEV[1];
    const int nch = (V + 63) >> 6;
    __syncthreads();

    if (t < 64) {   // wave 0 resolves alone; all state logically uniform except per-lane words
        u64 remA = 0, remB = 0, carry = 0;
        u64 pendA[PCAP], pendB[PCAP];
#pragma unroll
        for (int k = 0; k < PCAP; ++k) { pendA[k] = 0; pendB[k] = 0; }
        int np = 0;
        u64 d0 = 0, d1 = 0;             // diag pair for current chunk's rows (per-lane)
        if (lane < V) {
            d0 = D0[lane];
            if (nch > 1) d1 = D1[lane];
        }
        int nkept = 0;
        for (int c = 0; c < nch; ++c) {
            // removed word c: lagged rows (rounds <= c-2) via remA/remB, round c-1 via carry
            u64 rw = ((c < 64) ? __shfl(remA, c) : __shfl(remB, c - 64)) | carry;
            int rem_n = V - c * 64;
            u64 aliveM = (rem_n >= 64) ? ~0ULL : ((1ULL << rem_n) - 1ULL);
            u64 cand = ~rw & aliveM;
            // prefetch next chunk's diag pair (coalesced; independent of resolve)
            u64 nd0 = 0, nd1 = 0;
            if (c + 1 < nch) {
                int idx = (c + 1) * 64 + lane;
                if (idx < V) {
                    nd0 = D0[idx];
                    if (c + 2 < nch) nd1 = D1[idx];
                }
            }
            // greedy resolve within chunk (exact rank order); carry built in same loop
            u64 kb = 0, ncarry = 0;
            while (cand) {
                int b = __builtin_ctzll(cand);
                kb |= (1ULL << b);
                cand &= ~((1ULL << b) | __shfl(d0, b));
                ncarry |= __shfl(d1, b);
            }
            if (lane == 0) keepw[c] = kb;
            nkept += __popcll(kb);
            // apply previous round's kept-row loads (~1 round of latency slack)
#pragma unroll
            for (int k = 0; k < PCAP; ++k)
                if (k < np) { remA |= pendA[k]; remB |= pendB[k]; }
            // issue this round's kept-row loads into fixed registers (static indexing)
            u64 kk = kb;
            int nn = 0;
#pragma unroll
            for (int k = 0; k < PCAP; ++k) {
                if (kk) {
                    int b = __builtin_ctzll(kk);
                    kk &= kk - 1;
                    const u64* row = M + (u64)(c * 64 + b) * NCHK;
                    pendA[k] = row[lane];
                    pendB[k] = (lane + 64 < NCHK) ? row[lane + 64] : 0;
                    ++nn;
                }
            }
            np = nn;
            while (kk) {   // overflow (>PCAP kept in one chunk, rare): apply immediately
                int b = __builtin_ctzll(kk);
                kk &= kk - 1;
                const u64* row = M + (u64)(c * 64 + b) * NCHK;
                remA |= row[lane];
                if (lane + 64 < NCHK) remB |= row[lane + 64];
            }
            carry = ncarry;
            d0 = nd0;
            d1 = nd1;
            if (nkept >= NOUT) break;   // later keepw stay 0; first 300 kept unaffected
        }
    }
    __syncthreads();

    // Phase 2: out[pos] = kept boxes in rank order, then not-kept (suppressed or rank>=V)
    // in rank order, filling up to 300. One scan gives both prefixes.
    const int per = 6;                  // 1024*6 >= 6000
    int r0 = t * per;
    int r1 = min(r0 + per, KTOP);
    u32 cnt = 0;
    for (int r = r0; r < r1; ++r)
        cnt += (u32)((keepw[r >> 6] >> (r & 63)) & 1ULL);
    scanbuf[t] = cnt;
    __syncthreads();
    for (int d = 1; d < 1024; d <<= 1) {
        u32 v = (t >= d) ? scanbuf[t - d] : 0;
        __syncthreads();
        scanbuf[t] += v;
        __syncthreads();
    }
    const int total = (int)scanbuf[1023];
    const int n1 = min(total, NOUT);
    int kp = (int)(scanbuf[t] - cnt);   // kept before r0
    for (int r = r0; r < r1; ++r) {
        int kept = (int)((keepw[r >> 6] >> (r & 63)) & 1ULL);
        int pos = kept ? kp : (n1 + r - kp);   // not-kept before r = r - kp
        if (pos < NOUT) {
            float4 b = topBoxes[r];
            out[pos * 5 + 0] = 0.f;
            out[pos * 5 + 1] = b.x;
            out[pos * 5 + 2] = b.y;
            out[pos * 5 + 3] = b.z;
            out[pos * 5 + 4] = b.w;
        }
        kp += kept;
    }
}

extern "C" void kernel_launch(void* const* d_in, const int* in_sizes, int n_in,
                              void* d_out, int out_size, void* d_ws, size_t ws_size,
                              hipStream_t stream) {
    const float* cls = (const float*)d_in[0];   // (1,64,64,18) f32
    const float* dlt = (const float*)d_in[1];   // (1,64,64,36) f32
    float* out = (float*)d_out;                 // 300x5 f32
    char* ws = (char*)d_ws;
    // layout (16B-aligned offsets); hist and cursor adjacent -> single memset.
    // Total footprint ~5.95 MB (mask matrix M dominates).
    u64*    keys     = (u64*)   (ws);                    // 294912
    u64*    scat     = (u64*)   (ws + 294912);           // 294912
    float4* boxes    = (float4*)(ws + 589824);           // 589824
    float4* topBoxes = (float4*)(ws + 1179648);          // 96000
    u32*    hist     = (u32*)   (ws + 1275648);          // 20480
    u32*    cursor   = (u32*)   (ws + 1296128);          // 20480
    u32*    binStart = (u32*)   (ws + 1316608);          // 20480
    u32*    gEV      = (u32*)   (ws + 1337088);          // [0]=E, [1]=V
    u64*    D0       = (u64*)   (ws + 1337344);          // 48000 (diag words)
    u64*    D1       = (u64*)   (ws + 1385344);          // 48000 (diag+1 words)
    u64*    M        = (u64*)   (ws + 1433344);          // 4512000 (6000 x 94 words)

    hipMemsetAsync(hist, 0, 2 * NBIN * sizeof(u32), stream);   // hist + cursor
    proposal_kernel<<<36, 1024, 0, stream>>>(cls, dlt, keys, boxes, hist);
    scan_kernel<<<1, 1024, 0, stream>>>(hist, binStart, gEV);
    scatter_kernel<<<(N_ANCH + 255) / 256, 256, 0, stream>>>(keys, binStart, cursor, scat);
    rank_kernel<<<(N_ANCH + 255) / 256, 256, 0, stream>>>(scat, binStart, hist, boxes, gEV,
                                                          topBoxes, (int*)&gEV[1]);
    mask_kernel<<<dim3(NCHK, (NCHK + 3) / 4), 256, 0, stream>>>(topBoxes, gEV, M, D0, D1);
    nms_out_kernel<<<1, 1024, 0, stream>>>(topBoxes, gEV, M, D0, D1, out);
}

// Round 2
// 120.989 us; speedup vs baseline: 1.8297x; 1.8297x over previous
//
#include <hip/hip_runtime.h>
#include <stdint.h>

typedef unsigned long long u64;
typedef unsigned int u32;

#define N_ANCH 36864
#define WGRID 64
#define A_PER 9
#define KTOP 6000
#define NOUT 300
#define NBIN 5120       // max used bin = 4352 (binof), multiple of 1024 for scan
#define NCHK 94         // ceil(6000/64) = u64 words
#define NJ   6016       // padded j-stride of S (u64 words, 64-multiple >= 6000)
#define INF_BIN 0       // -inf / invalid scores
#define PCAP 6          // per-wave word slots: w = wave + 16*k, k<6 covers w<94

// Base anchors from py-faster-rcnn generate_anchors (scales 8,16,32; ratios .5,1,2), exact integers.
__constant__ float c_ax1[9] = {-84.f,-176.f,-360.f,-56.f,-120.f,-248.f,-36.f,-80.f,-168.f};
__constant__ float c_ay1[9] = {-40.f,-88.f,-184.f,-56.f,-120.f,-248.f,-80.f,-168.f,-344.f};
__constant__ float c_aw[9]  = {184.f,368.f,736.f,128.f,256.f,512.f,88.f,176.f,352.f};
__constant__ float c_ah[9]  = {96.f,192.f,384.f,128.f,256.f,512.f,176.f,352.f,704.f};

// Monotone (order-preserving) bin of the ordered-float score word u = key>>32.
__device__ __forceinline__ u32 binof(u32 u) {
    if (u < 0x80000000u) return 0u;                          // -inf (invalid)
    if (u < 0xBF000000u) return 1u + ((u - 0x80000000u) >> 22);   // s<0.5 : 1..252
    return 256u + ((u - 0xBF000000u) >> 11);                 // s>=0.5: 256..4352
}

// 144 blocks x 256 threads = 36864 (spread the expf-heavy phase over 144 CUs).
__global__ __launch_bounds__(256) void proposal_kernel(const float* __restrict__ cls,
                                                       const float* __restrict__ dlt,
                                                       u64* __restrict__ keys,
                                                       float4* __restrict__ boxes,
                                                       u32* __restrict__ hist) {
    __shared__ u32 lh[NBIN];
    const int t = threadIdx.x;
    for (int b = t; b < NBIN; b += 256) lh[b] = 0;
    __syncthreads();

    int i = blockIdx.x * 256 + t;
    int a  = i % A_PER;
    int hw = i / A_PER;
    int wx = hw % WGRID;
    int hy = hw / WGRID;

    float2 lp = *(const float2*)(cls + hw * 18 + 2 * a);
    float l0 = lp.x, l1 = lp.y;
    float m  = fmaxf(l0, l1);
    float e0 = expf(l0 - m), e1 = expf(l1 - m);
    float s  = e1 / (e0 + e1);

    float4 dd = *(const float4*)(dlt + hw * 36 + 4 * a);
    float dx = dd.x, dy = dd.y, dw = dd.z, dh = dd.w;
    float aw = c_aw[a], ah = c_ah[a];
    float axc = (c_ax1[a] + 16.f * (float)wx) + 0.5f * aw;
    float ayc = (c_ay1[a] + 16.f * (float)hy) + 0.5f * ah;

    float pxc = dx * aw + axc;
    float pyc = dy * ah + ayc;
    float pw  = expf(dw) * aw;
    float ph  = expf(dh) * ah;
    float x1 = pxc - 0.5f * pw, y1 = pyc - 0.5f * ph;
    float x2 = pxc + 0.5f * pw, y2 = pyc + 0.5f * ph;
    x1 = fminf(fmaxf(x1, 0.f), 1023.f);
    x2 = fminf(fmaxf(x2, 0.f), 1023.f);
    y1 = fminf(fmaxf(y1, 0.f), 1023.f);
    y2 = fminf(fmaxf(y2, 0.f), 1023.f);
    bool valid = ((x2 - x1 + 1.f) >= 16.f) && ((y2 - y1 + 1.f) >= 16.f);
    float sc = valid ? s : -__builtin_huge_valf();

    u32 sb  = __float_as_uint(sc);
    u32 ord = (sb & 0x80000000u) ? ~sb : (sb | 0x80000000u);
    u64 key = ((u64)ord << 32) | (u32)(~(u32)i);
    keys[i]  = key;
    boxes[i] = make_float4(x1, y1, x2, y2);

    u64 infb = __ballot(!valid);
    if (valid) {
        atomicAdd(&lh[binof(ord)], 1u);
    } else {
        int lane = t & 63;
        if (lane == __builtin_ctzll(infb))
            atomicAdd(&lh[INF_BIN], (u32)__popcll(infb));
    }
    __syncthreads();
    for (int b = t; b < NBIN; b += 256) {
        u32 v = lh[b];
        if (v) atomicAdd(&hist[b], v);
    }
}

__global__ __launch_bounds__(1024) void scan_kernel(const u32* __restrict__ hist,
                                                    u32* __restrict__ binStart,
                                                    u32* __restrict__ gEV) {
    __shared__ u32 sh[1024];
    int t = threadIdx.x;
    if (t == 0) gEV[1] = KTOP;
    int hi = NBIN - 1 - 5 * t;
    u32 cnt[5];
    u32 sum = 0;
#pragma unroll
    for (int k = 0; k < 5; ++k) { cnt[k] = hist[hi - k]; sum += cnt[k]; }
    sh[t] = sum;
    __syncthreads();
    for (int d = 1; d < 1024; d <<= 1) {
        u32 v = (t >= d) ? sh[t - d] : 0;
        __syncthreads();
        sh[t] += v;
        __syncthreads();
    }
    u32 run = sh[t] - sum;
#pragma unroll
    for (int k = 0; k < 5; ++k) {
        int b = hi - k;
        binStart[b] = run;
        u32 end = run + cnt[k];
        if (run < KTOP && end >= KTOP) gEV[0] = end;
        run = end;
    }
}

__global__ void scatter_kernel(const u64* __restrict__ keys,
                               const u32* __restrict__ binStart,
                               u32* __restrict__ cursor,
                               u64* __restrict__ scat) {
    int i = blockIdx.x * blockDim.x + threadIdx.x;
    if (i >= N_ANCH) return;
    u64 k = keys[i];
    u32 b = binof((u32)(k >> 32));
    u32 s = binStart[b];
    if (s < KTOP) {
        u32 p = s + atomicAdd(&cursor[b], 1u);
        scat[p] = k;
    }
}

__global__ void rank_kernel(const u64* __restrict__ scat,
                            const u32* __restrict__ binStart,
                            const u32* __restrict__ hist,
                            const float4* __restrict__ boxes,
                            const u32* __restrict__ gEV,
                            float4* __restrict__ topBoxes,
                            int* __restrict__ gV) {
    int i = blockIdx.x * blockDim.x + threadIdx.x;
    u32 E = gEV[0];
    if (i >= (int)E) return;
    u64 k = scat[i];
    u32 b = binof((u32)(k >> 32));
    u32 s = binStart[b], c = hist[b];
    u32 r = s;
    for (u32 j = s; j < s + c; ++j) r += (scat[j] > k) ? 1u : 0u;
    if (r < KTOP) {
        int idx = (int)(~(u32)k);
        topBoxes[r] = boxes[idx];
        if (!(k >> 63)) atomicMin(gV, (int)r);
    }
}

__device__ __forceinline__ bool iou_gt(float4 a, float areaA, float4 b, float areaB) {
    float ix1 = fmaxf(a.x, b.x), iy1 = fmaxf(a.y, b.y);
    float ix2 = fminf(a.z, b.z), iy2 = fminf(a.w, b.w);
    float iw = fmaxf(ix2 - ix1 + 1.0f, 0.0f);
    float ih = fmaxf(iy2 - iy1 + 1.0f, 0.0f);
    float inter = iw * ih;
    float iou = inter / (areaA + areaB - inter);
    return iou > 0.7f;
}

// TRANSPOSED suppression mask: S[w][j] bit b = (IoU(box_{64w+b}, box_j) > 0.7) && (64w+b < j).
// Row w is contiguous in j -> the NMS kernel's per-round loads S[w][64c+lane] are coalesced
// AND their addresses are independent of which boxes get kept -> prefetchable 2 rounds deep.
__global__ __launch_bounds__(256) void maskT_kernel(const float4* __restrict__ topBoxes,
                                                    const u32* __restrict__ gEV,
                                                    u64* __restrict__ S) {
    const int V = (int)gEV[1];
    const int nch = (V + 63) >> 6;
    const int jc = blockIdx.x;               // j-chunk (column group of 64 boxes)
    const int w0 = blockIdx.y * 4;           // first i-word of this block
    if (jc >= nch || w0 > jc) return;        // only w <= jc needed (i < j)
    __shared__ float4 cb[256];
    __shared__ float  ca[256];
    const int t = threadIdx.x;
    const int lane = t & 63;
    {
        int ci = w0 * 64 + t;
        // dummy for i >= V: inverted box -> intersection 0 -> never suppresses
        float4 b = (ci < V) ? topBoxes[ci] : make_float4(0.f, 0.f, -8.f, -8.f);
        cb[t] = b;
        ca[t] = (b.z - b.x + 1.f) * (b.w - b.y + 1.f);
    }
    __syncthreads();
    const int w = w0 + (t >> 6);
    if (w > jc || w >= nch) return;
    const int j = jc * 64 + lane;
    float4 bj = (j < V) ? topBoxes[j] : make_float4(0.f, 0.f, -8.f, -8.f);
    float aj = (bj.z - bj.x + 1.f) * (bj.w - bj.y + 1.f);
    const int s0 = (t >> 6) * 64;
    u64 m = 0;
#pragma unroll 4
    for (int b = 0; b < 64; ++b)
        if (iou_gt(bj, aj, cb[s0 + b], ca[s0 + b])) m |= (1ull << b);
    if (w == jc) m &= ((1ull << lane) - 1ull);   // diagonal word: keep only i < j
    S[(u64)w * NJ + j] = m;
}

// Single block, 1024 threads, EXACT greedy NMS over the transposed mask.
// Round c: suppressed(j) = OR_{w<c}( S[w][j] & keepw[w] ).  16 waves each own words
// w = wave + 16k (k<6): S words prefetched 2 rounds ahead into registers (addresses are
// kept-independent!), ANDed with cached keepw, combined via one __ballot per wave into
// supw[16]. Wave 0 then resolves intra-chunk order with the diagonal word dT and
// cand &= ~ballot((dT>>b)&1). No global-memory latency on the serial critical path.
__global__ __launch_bounds__(1024) void nms_out_kernel(const float4* __restrict__ topBoxes,
                                                       const u32* __restrict__ gEV,
                                                       const u64* __restrict__ S,
                                                       float* __restrict__ out) {
    __shared__ u64 keepw[NCHK];
    __shared__ u64 supw[16];
    __shared__ u32 scanbuf[1024];
    __shared__ int s_nkept;
    const int t = threadIdx.x;
    const int lane = t & 63;
    const int v = t >> 6;                    // wave id, 16 waves
    if (t < NCHK) keepw[t] = 0;
    if (t == 0) s_nkept = 0;
    const int V = (int)gEV[1];
    const int nch = (V + 63) >> 6;

    u64 kw[PCAP], pendE[PCAP], pendO[PCAP];  // cached keep-words + double-buffered S words
#pragma unroll
    for (int k = 0; k < PCAP; ++k) { kw[k] = 0; pendE[k] = 0; pendO[k] = 0; }
    u64 dtE = 0, dtO = 0;                    // wave-0 diagonal prefetch (parity-buffered)
    // prologue: round 0 needs no earlier words; round 1 needs w=0 only
#pragma unroll
    for (int k = 0; k < PCAP; ++k) {
        int w = v + 16 * k;
        if (w < 1 && 1 < nch) pendO[k] = S[(u64)w * NJ + 64 + lane];
    }
    if (v == 0) {
        dtE = S[lane];                       // S[0][lane]
        if (nch > 1) dtO = S[(u64)NJ + 64 + lane];
    }
    __syncthreads();

    for (int c = 0; c < nch; ++c) {
        if (s_nkept >= NOUT) break;          // uniform (post-barrier LDS read)
        // cache the keep-word finalized last round (w == c-1); stale pend slots with
        // w >= c are harmless: their kw[k] is still 0.
#pragma unroll
        for (int k = 0; k < PCAP; ++k) {
            int w = v + 16 * k;
            if (w == c - 1) kw[k] = keepw[w];
        }
        u64 acc = 0;
        if (c & 1) {
#pragma unroll
            for (int k = 0; k < PCAP; ++k) { int w = v + 16 * k; if (w < c) acc |= pendO[k] & kw[k]; }
        } else {
#pragma unroll
            for (int k = 0; k < PCAP; ++k) { int w = v + 16 * k; if (w < c) acc |= pendE[k] & kw[k]; }
        }
        u64 bal = __ballot(acc != 0ull);
        if (lane == 0) supw[v] = bal;
        // refill the just-applied buffer for round c+2 (depth-2 prefetch, ~2 rounds of cover)
        const int cn = c + 2;
        if (cn < nch) {
            const u64* Sc = S + (u64)cn * 64 + lane;
            if (c & 1) {
#pragma unroll
                for (int k = 0; k < PCAP; ++k) { int w = v + 16 * k; if (w < cn) pendO[k] = Sc[(u64)w * NJ]; }
            } else {
#pragma unroll
                for (int k = 0; k < PCAP; ++k) { int w = v + 16 * k; if (w < cn) pendE[k] = Sc[(u64)w * NJ]; }
            }
        }
        __syncthreads();                     // B2: supw ready
        if (v == 0) {
            u64 sup = 0;
#pragma unroll
            for (int q = 0; q < 16; ++q) sup |= supw[q];
            int rem = V - c * 64;
            u64 aliveM = (rem >= 64) ? ~0ull : ((1ull << rem) - 1ull);
            u64 cand = ~sup & aliveM;
            u64 dT = (c & 1) ? dtO : dtE;
            u64 kb = 0;
            while (cand) {
                int b = __builtin_ctzll(cand);
                kb |= (1ull << b);
                cand &= ~(1ull << b);
                cand &= ~__ballot(((dT >> b) & 1ull) != 0ull);
            }
            if (lane == 0) { keepw[c] = kb; s_nkept += __popcll(kb); }
            if (cn < nch) {                  // refill diagonal AFTER use
                u64 dload = S[(u64)cn * NJ + (u64)cn * 64 + lane];
                if (c & 1) dtO = dload; else dtE = dload;
            }
        }
        __syncthreads();                     // B3: keepw[c] / s_nkept visible next round
    }
    __syncthreads();

    // Phase 2: out[pos] = kept boxes in rank order, then not-kept (suppressed or rank>=V)
    // in rank order, filling up to 300. One scan gives both prefixes. (verified semantics)
    const int per = 6;                       // 1024*6 >= 6000
    int r0 = t * per;
    int r1 = min(r0 + per, KTOP);
    u32 cnt = 0;
    for (int r = r0; r < r1; ++r)
        cnt += (u32)((keepw[r >> 6] >> (r & 63)) & 1ull);
    scanbuf[t] = cnt;
    __syncthreads();
    for (int d = 1; d < 1024; d <<= 1) {
        u32 vv = (t >= d) ? scanbuf[t - d] : 0;
        __syncthreads();
        scanbuf[t] += vv;
        __syncthreads();
    }
    const int total = (int)scanbuf[1023];
    const int n1 = min(total, NOUT);
    int kp = (int)(scanbuf[t] - cnt);        // kept before r0
    for (int r = r0; r < r1; ++r) {
        int kept = (int)((keepw[r >> 6] >> (r & 63)) & 1ull);
        int pos = kept ? kp : (n1 + r - kp); // not-kept before r = r - kp
        if (pos < NOUT) {
            float4 b = topBoxes[r];
            out[pos * 5 + 0] = 0.f;
            out[pos * 5 + 1] = b.x;
            out[pos * 5 + 2] = b.y;
            out[pos * 5 + 3] = b.z;
            out[pos * 5 + 4] = b.w;
        }
        kp += kept;
    }
}

extern "C" void kernel_launch(void* const* d_in, const int* in_sizes, int n_in,
                              void* d_out, int out_size, void* d_ws, size_t ws_size,
                              hipStream_t stream) {
    const float* cls = (const float*)d_in[0];   // (1,64,64,18) f32
    const float* dlt = (const float*)d_in[1];   // (1,64,64,36) f32
    float* out = (float*)d_out;                 // 300x5 f32
    char* ws = (char*)d_ws;
    // layout (16B-aligned offsets); hist and cursor adjacent -> single memset.
    // Total footprint ~5.86 MB (transposed mask S dominates).
    u64*    keys     = (u64*)   (ws);                    // 294912
    u64*    scat     = (u64*)   (ws + 294912);           // 294912
    float4* boxes    = (float4*)(ws + 589824);           // 589824
    float4* topBoxes = (float4*)(ws + 1179648);          // 96000
    u32*    hist     = (u32*)   (ws + 1275648);          // 20480
    u32*    cursor   = (u32*)   (ws + 1296128);          // 20480
    u32*    binStart = (u32*)   (ws + 1316608);          // 20480
    u32*    gEV      = (u32*)   (ws + 1337088);          // [0]=E, [1]=V (+pad)
    u64*    S        = (u64*)   (ws + 1337344);          // 4524032 (94 x 6016 words)

    hipMemsetAsync(hist, 0, 2 * NBIN * sizeof(u32), stream);   // hist + cursor
    proposal_kernel<<<144, 256, 0, stream>>>(cls, dlt, keys, boxes, hist);
    scan_kernel<<<1, 1024, 0, stream>>>(hist, binStart, gEV);
    scatter_kernel<<<(N_ANCH + 255) / 256, 256, 0, stream>>>(keys, binStart, cursor, scat);
    rank_kernel<<<(N_ANCH + 255) / 256, 256, 0, stream>>>(scat, binStart, hist, boxes, gEV,
                                                          topBoxes, (int*)&gEV[1]);
    maskT_kernel<<<dim3(NCHK, (NCHK + 3) / 4), 256, 0, stream>>>(topBoxes, gEV, S);
    nms_out_kernel<<<1, 1024, 0, stream>>>(topBoxes, gEV, S, out);
}